// Round 1
// baseline (1113.792 us; speedup 1.0000x reference)
//
#include <hip/hip_runtime.h>

#define NNODE 262144
#define NEDGE 1048576
#define NTILES (NEDGE / 128)
#define NEG 0.01f

typedef __bf16 bf16x8 __attribute__((ext_vector_type(8)));
typedef float f32x4 __attribute__((ext_vector_type(4)));
typedef unsigned short u16;
typedef unsigned int u32;

__device__ __forceinline__ u16 f2bf(float f) {
    u32 u = __float_as_uint(f);
    u = u + 0x7FFFu + ((u >> 16) & 1u);   // RNE
    return (u16)(u >> 16);
}
// order-preserving float->uint encoding for atomicMax; key 0 == "empty" (< any real value)
__device__ __forceinline__ u32 encf(float f) {
    u32 u = __float_as_uint(f);
    return (u & 0x80000000u) ? ~u : (u | 0x80000000u);
}
__device__ __forceinline__ float decf(u32 k) {
    return (k & 0x80000000u) ? __uint_as_float(k ^ 0x80000000u) : __uint_as_float(~k);
}
__device__ __forceinline__ float lrelu(float x) { return x >= 0.f ? x : NEG * x; }

// ---------------- K1: init out / gmax / denom (+ optional bf16 fea table) ----------------
template <bool TAB>
__global__ void k_init(const float* __restrict__ fea, float* __restrict__ out,
                       u32* __restrict__ gmaxk, float* __restrict__ denom,
                       u16* __restrict__ fea16) {
    int i = blockIdx.x * 256 + threadIdx.x;         // exactly N*16 float4 units
    float4 v = ((const float4*)fea)[i];
    ((float4*)out)[i] = v;                          // out starts at elem_in_fea
    if (TAB) {
        ushort4 s;
        s.x = f2bf(v.x); s.y = f2bf(v.y); s.z = f2bf(v.z); s.w = f2bf(v.w);
        ((ushort4*)fea16)[i] = s;
    }
    if (i < 3 * NNODE) { gmaxk[i] = 0u; denom[i] = 0.f; }
}

// ---------------- staging helper: 128 edges x 128 cols bf16 into LDS (pad 136) ----------------
template <bool TAB>
__device__ __forceinline__ void stage_A(u16* Al, int tile, int tid,
                                        const float* __restrict__ fea,
                                        const u16* __restrict__ fea16,
                                        const int* __restrict__ selfi,
                                        const int* __restrict__ nbri) {
#pragma unroll
    for (int it = 0; it < 8; ++it) {
        int idx = tid + it * 512;          // 0..4095
        int el = idx >> 5;                 // edge-local 0..127
        int part = idx & 31;               // 0..15 self, 16..31 nbr
        int edge = tile * 128 + el;
        int node = (part < 16) ? selfi[edge] : nbri[edge];
        int c4 = (part & 15) << 2;         // feature col within node (x4)
        int col0 = ((part >> 4) << 6) + c4;
        ushort4 sv;
        if (TAB) {
            sv = *(const ushort4*)(fea16 + node * 64 + c4);
        } else {
            float4 fv = *(const float4*)(fea + node * 64 + c4);
            sv.x = f2bf(fv.x); sv.y = f2bf(fv.y); sv.z = f2bf(fv.z); sv.w = f2bf(fv.w);
        }
        *(ushort4*)(Al + el * 136 + col0) = sv;
    }
}

// ---------------- K2: gate logits g[h][e] + segment max ----------------
template <bool TAB>
__global__ __launch_bounds__(512) void k_gate(
    const float* __restrict__ fea, const u16* __restrict__ fea16,
    const int* __restrict__ selfi, const int* __restrict__ nbri,
    const float* __restrict__ gw1, const float* __restrict__ gb1,
    const float* __restrict__ gw2, const float* __restrict__ gb2,
    float* __restrict__ g_out, u32* __restrict__ gmaxk) {
    __shared__ u16 Wl[128 * 136];   // gate_w1[h] as [n][k], padded
    __shared__ u16 Al[128 * 136];   // edge tile [e][k], padded
    const int h = blockIdx.y;
    const int tid = threadIdx.x;
    const int l = tid & 63, w = tid >> 6, q = l >> 4, c = l & 15;

#pragma unroll
    for (int it = 0; it < 32; ++it) {
        int i = tid + it * 512;            // over [k][n], coalesced global read
        int k = i >> 7, n = i & 127;
        Wl[n * 136 + k] = f2bf(gw1[h * 16384 + i]);
    }
    float b1v[8], w2v[8];
#pragma unroll
    for (int nt = 0; nt < 8; ++nt) {
        b1v[nt] = gb1[h * 128 + nt * 16 + c];
        w2v[nt] = gw2[h * 128 + nt * 16 + c];
    }
    const float b2s = gb2[h];
    __syncthreads();

    for (int tile = blockIdx.x; tile < NTILES; tile += gridDim.x) {
        stage_A<TAB>(Al, tile, tid, fea, fea16, selfi, nbri);
        __syncthreads();

        const u16* arow = Al + (w * 16 + c) * 136 + q * 8;
        bf16x8 af0 = *(const bf16x8*)(arow);
        bf16x8 af1 = *(const bf16x8*)(arow + 32);
        bf16x8 af2 = *(const bf16x8*)(arow + 64);
        bf16x8 af3 = *(const bf16x8*)(arow + 96);

        float gp0 = b2s, gp1 = b2s, gp2 = b2s, gp3 = b2s;
#pragma unroll
        for (int nt = 0; nt < 8; ++nt) {
            const u16* bp = Wl + (nt * 16 + c) * 136 + q * 8;
            f32x4 acc = {0.f, 0.f, 0.f, 0.f};
            acc = __builtin_amdgcn_mfma_f32_16x16x32_bf16(af0, *(const bf16x8*)(bp), acc, 0, 0, 0);
            acc = __builtin_amdgcn_mfma_f32_16x16x32_bf16(af1, *(const bf16x8*)(bp + 32), acc, 0, 0, 0);
            acc = __builtin_amdgcn_mfma_f32_16x16x32_bf16(af2, *(const bf16x8*)(bp + 64), acc, 0, 0, 0);
            acc = __builtin_amdgcn_mfma_f32_16x16x32_bf16(af3, *(const bf16x8*)(bp + 96), acc, 0, 0, 0);
            gp0 += lrelu(acc[0] + b1v[nt]) * w2v[nt];
            gp1 += lrelu(acc[1] + b1v[nt]) * w2v[nt];
            gp2 += lrelu(acc[2] + b1v[nt]) * w2v[nt];
            gp3 += lrelu(acc[3] + b1v[nt]) * w2v[nt];
        }
        // reduce across the 16 lanes (c = 0..15) that share the same 4 edge-rows
#pragma unroll
        for (int m = 1; m < 16; m <<= 1) {
            gp0 += __shfl_xor(gp0, m, 64);
            gp1 += __shfl_xor(gp1, m, 64);
            gp2 += __shfl_xor(gp2, m, 64);
            gp3 += __shfl_xor(gp3, m, 64);
        }
        if (c == 0) {
            int e0 = tile * 128 + w * 16 + q * 4;
            float gp[4] = {gp0, gp1, gp2, gp3};
#pragma unroll
            for (int r = 0; r < 4; ++r) {
                float gv = gp[r];
                g_out[h * NEDGE + e0 + r] = gv;
                atomicMax(gmaxk + h * NNODE + selfi[e0 + r], encf(gv));
            }
        }
        __syncthreads();
    }
}

// ---------------- K3: e = w*exp(g-gmax) (in place), denom += e ----------------
__global__ void k_denom(const float* __restrict__ ew,
                        const int* __restrict__ selfi, const int* __restrict__ nbri,
                        float* __restrict__ e_buf, const u32* __restrict__ gmaxk,
                        float* __restrict__ denom) {
    int e = blockIdx.x * 256 + threadIdx.x;   // exactly M threads
    int s = selfi[e], nb = nbri[e];
    float wv = ew[nb];                         // WEIGHT_POW == 1.0
#pragma unroll
    for (int h = 0; h < 3; ++h) {
        float gv = e_buf[h * NEDGE + e];
        float mx = decf(gmaxk[h * NNODE + s]);
        float ev = wv * __expf(gv - mx);
        e_buf[h * NEDGE + e] = ev;
        atomicAdd(denom + h * NNODE + s, ev);
    }
}

// ---------------- K4: messages + attn scatter ----------------
template <bool TAB>
__global__ __launch_bounds__(512) void k_msg(
    const float* __restrict__ fea, const u16* __restrict__ fea16,
    const int* __restrict__ selfi, const int* __restrict__ nbri,
    const float* __restrict__ mw1, const float* __restrict__ mb1,
    const float* __restrict__ mw2, const float* __restrict__ mb2,
    const float* __restrict__ e_buf, const float* __restrict__ denom,
    float* __restrict__ out) {
    __shared__ u16 W1l[128 * 136];       // msg_w1[h] as [n][k]
    __shared__ u16 W2l[64 * 136];        // msg_w2[h] as [n][k]
    __shared__ u16 Al[128 * 136];
    __shared__ u16 Hl[8][16 * 40];       // per-wave hidden ping buffer (16 rows x 32 cols, pad 40)
    __shared__ float attn_l[128];
    __shared__ int self_l[128];
    const int h = blockIdx.y;
    const int tid = threadIdx.x;
    const int l = tid & 63, w = tid >> 6, q = l >> 4, c = l & 15;

#pragma unroll
    for (int it = 0; it < 32; ++it) {
        int i = tid + it * 512;
        int k = i >> 7, n = i & 127;
        W1l[n * 136 + k] = f2bf(mw1[h * 16384 + i]);
    }
#pragma unroll
    for (int it = 0; it < 16; ++it) {
        int i = tid + it * 512;
        int k = i >> 6, n = i & 63;
        W2l[n * 136 + k] = f2bf(mw2[h * 8192 + i]);
    }
    float b1v[8], b2v[4];
#pragma unroll
    for (int nt = 0; nt < 8; ++nt) b1v[nt] = mb1[h * 128 + nt * 16 + c];
#pragma unroll
    for (int n2 = 0; n2 < 4; ++n2) b2v[n2] = mb2[h * 64 + n2 * 16 + c];
    __syncthreads();

    for (int tile = blockIdx.x; tile < NTILES; tile += gridDim.x) {
        stage_A<TAB>(Al, tile, tid, fea, fea16, selfi, nbri);
        if (tid < 128) {
            int e = tile * 128 + tid;
            int s = selfi[e];
            self_l[tid] = s;
            attn_l[tid] = e_buf[h * NEDGE + e] / (denom[h * NNODE + s] + 1e-10f) * (1.f / 3.f);
        }
        __syncthreads();

        const u16* arow = Al + (w * 16 + c) * 136 + q * 8;
        bf16x8 af0 = *(const bf16x8*)(arow);
        bf16x8 af1 = *(const bf16x8*)(arow + 32);
        bf16x8 af2 = *(const bf16x8*)(arow + 64);
        bf16x8 af3 = *(const bf16x8*)(arow + 96);

        f32x4 m0 = {0.f, 0.f, 0.f, 0.f}, m1 = m0, m2 = m0, m3 = m0;
        u16* hb = &Hl[w][0];
#pragma unroll
        for (int kk2 = 0; kk2 < 4; ++kk2) {
#pragma unroll
            for (int half = 0; half < 2; ++half) {
                int nt = kk2 * 2 + half;
                const u16* bp = W1l + (nt * 16 + c) * 136 + q * 8;
                f32x4 acc = {0.f, 0.f, 0.f, 0.f};
                acc = __builtin_amdgcn_mfma_f32_16x16x32_bf16(af0, *(const bf16x8*)(bp), acc, 0, 0, 0);
                acc = __builtin_amdgcn_mfma_f32_16x16x32_bf16(af1, *(const bf16x8*)(bp + 32), acc, 0, 0, 0);
                acc = __builtin_amdgcn_mfma_f32_16x16x32_bf16(af2, *(const bf16x8*)(bp + 64), acc, 0, 0, 0);
                acc = __builtin_amdgcn_mfma_f32_16x16x32_bf16(af3, *(const bf16x8*)(bp + 96), acc, 0, 0, 0);
#pragma unroll
                for (int r = 0; r < 4; ++r) {
                    float hv = lrelu(acc[r] + b1v[nt]);
                    hb[(q * 4 + r) * 40 + half * 16 + c] = f2bf(hv);
                }
            }
            // wave-private LDS ping: ensure writes land before cross-lane read
            asm volatile("s_waitcnt lgkmcnt(0)" ::: "memory");
            __builtin_amdgcn_sched_barrier(0);
            bf16x8 a2 = *(const bf16x8*)(hb + c * 40 + q * 8);
            const u16* w2base = W2l + c * 136 + kk2 * 32 + q * 8;
            m0 = __builtin_amdgcn_mfma_f32_16x16x32_bf16(a2, *(const bf16x8*)(w2base), m0, 0, 0, 0);
            m1 = __builtin_amdgcn_mfma_f32_16x16x32_bf16(a2, *(const bf16x8*)(w2base + 16 * 136), m1, 0, 0, 0);
            m2 = __builtin_amdgcn_mfma_f32_16x16x32_bf16(a2, *(const bf16x8*)(w2base + 32 * 136), m2, 0, 0, 0);
            m3 = __builtin_amdgcn_mfma_f32_16x16x32_bf16(a2, *(const bf16x8*)(w2base + 48 * 136), m3, 0, 0, 0);
        }
        // epilogue: attn*(m+b2), combine runs of equal self (sorted), scatter
        int rb = w * 16 + q * 4;
        int s0 = self_l[rb], s1 = self_l[rb + 1], s2 = self_l[rb + 2], s3 = self_l[rb + 3];
        float a0 = attn_l[rb], a1 = attn_l[rb + 1], a2v = attn_l[rb + 2], a3 = attn_l[rb + 3];
#pragma unroll
        for (int n2 = 0; n2 < 4; ++n2) {
            f32x4 mm = (n2 == 0) ? m0 : (n2 == 1) ? m1 : (n2 == 2) ? m2 : m3;
            int col = n2 * 16 + c;
            float v0 = a0 * (mm[0] + b2v[n2]);
            float v1 = a1 * (mm[1] + b2v[n2]);
            float v2 = a2v * (mm[2] + b2v[n2]);
            float v3 = a3 * (mm[3] + b2v[n2]);
            if (s0 == s1) v1 += v0; else atomicAdd(out + s0 * 64 + col, v0);
            if (s1 == s2) v2 += v1; else atomicAdd(out + s1 * 64 + col, v1);
            if (s2 == s3) v3 += v2; else atomicAdd(out + s2 * 64 + col, v2);
            atomicAdd(out + s3 * 64 + col, v3);
        }
        __syncthreads();
    }
}

extern "C" void kernel_launch(void* const* d_in, const int* in_sizes, int n_in,
                              void* d_out, int out_size, void* d_ws, size_t ws_size,
                              hipStream_t stream) {
    const float* ew   = (const float*)d_in[0];
    const float* fea  = (const float*)d_in[1];
    const int* selfi  = (const int*)d_in[2];
    const int* nbri   = (const int*)d_in[3];
    const float* gw1  = (const float*)d_in[4];
    const float* gb1  = (const float*)d_in[5];
    const float* gw2  = (const float*)d_in[6];
    const float* gb2  = (const float*)d_in[7];
    const float* mw1  = (const float*)d_in[8];
    const float* mb1  = (const float*)d_in[9];
    const float* mw2  = (const float*)d_in[10];
    const float* mb2  = (const float*)d_in[11];
    float* out = (float*)d_out;
    char* ws = (char*)d_ws;

    float* e_buf = (float*)ws;                 // 3*M f32   (g, then e in place)
    u32* gmaxk   = (u32*)(ws + 12582912);      // 3*N u32
    float* denom = (float*)(ws + 15728640);    // 3*N f32
    u16* fea16   = (u16*)(ws + 18874368);      // N*64 bf16 (optional)
    const bool tab = ws_size >= (size_t)52428800;

    if (tab) {
        k_init<true><<<dim3(16384), dim3(256), 0, stream>>>(fea, out, gmaxk, denom, fea16);
        k_gate<true><<<dim3(512, 3), dim3(512), 0, stream>>>(fea, fea16, selfi, nbri,
                                                             gw1, gb1, gw2, gb2, e_buf, gmaxk);
    } else {
        k_init<false><<<dim3(16384), dim3(256), 0, stream>>>(fea, out, gmaxk, denom, fea16);
        k_gate<false><<<dim3(512, 3), dim3(512), 0, stream>>>(fea, fea16, selfi, nbri,
                                                              gw1, gb1, gw2, gb2, e_buf, gmaxk);
    }
    k_denom<<<dim3(4096), dim3(256), 0, stream>>>(ew, selfi, nbri, e_buf, gmaxk, denom);
    if (tab) {
        k_msg<true><<<dim3(256, 3), dim3(512), 0, stream>>>(fea, fea16, selfi, nbri,
                                                            mw1, mb1, mw2, mb2, e_buf, denom, out);
    } else {
        k_msg<false><<<dim3(256, 3), dim3(512), 0, stream>>>(fea, fea16, selfi, nbri,
                                                             mw1, mb1, mw2, mb2, e_buf, denom, out);
    }
}

// Round 2
// 901.124 us; speedup vs baseline: 1.2360x; 1.2360x over previous
//
#include <hip/hip_runtime.h>

#define NNODE 262144
#define NEDGE 1048576
#define NTILES 8192
#define NEG 0.01f

typedef __bf16 bf16x8 __attribute__((ext_vector_type(8)));
typedef float f32x4 __attribute__((ext_vector_type(4)));
typedef unsigned short u16;
typedef u16 u16x8 __attribute__((ext_vector_type(8)));
typedef unsigned int u32;

__device__ __forceinline__ u16 f2bf(float f) {
    u32 u = __float_as_uint(f);
    u = u + 0x7FFFu + ((u >> 16) & 1u);   // RNE
    return (u16)(u >> 16);
}
// order-preserving float->uint encoding for atomicMax; key 0 == "empty"
__device__ __forceinline__ u32 encf(float f) {
    u32 u = __float_as_uint(f);
    return (u & 0x80000000u) ? ~u : (u | 0x80000000u);
}
__device__ __forceinline__ float decf(u32 k) {
    return (k & 0x80000000u) ? __uint_as_float(k ^ 0x80000000u) : __uint_as_float(~k);
}
__device__ __forceinline__ float lrelu(float x) { return x >= 0.f ? x : NEG * x; }

// load a B-operand MFMA fragment from a global f32 matrix stored [K][Ncols], ld = Ncols.
// fragment element j corresponds to k = k0 + q*8 + j, col = n  (p = W + k0*ld + n)
template <int LD>
__device__ __forceinline__ bf16x8 load_bfrag(const float* __restrict__ p) {
    u16x8 t;
#pragma unroll
    for (int j = 0; j < 8; ++j) t[j] = f2bf(p[j * LD]);
    return __builtin_bit_cast(bf16x8, t);
}

// ---------------- K1: init out / gmax / denom (+ optional bf16 fea table) ----------------
template <bool TAB>
__global__ void k_init(const float* __restrict__ fea, float* __restrict__ out,
                       u32* __restrict__ gmaxk, float* __restrict__ denom,
                       u16* __restrict__ fea16) {
    int i = blockIdx.x * 256 + threadIdx.x;         // exactly N*16 float4 units
    float4 v = ((const float4*)fea)[i];
    ((float4*)out)[i] = v;                          // out starts at elem_in_fea
    if (TAB) {
        ushort4 s;
        s.x = f2bf(v.x); s.y = f2bf(v.y); s.z = f2bf(v.z); s.w = f2bf(v.w);
        ((ushort4*)fea16)[i] = s;
    }
    if (i < 3 * NNODE) { gmaxk[i] = 0u; denom[i] = 0.f; }
}

// ---------------- staging: 128 edges x 128 cols bf16 into LDS (pad 136) ----------------
template <bool TAB, int NTHR>
__device__ __forceinline__ void stage_A(u16* Al, int tile, int tid,
                                        const float* __restrict__ fea,
                                        const u16* __restrict__ fea16,
                                        const int* __restrict__ selfi,
                                        const int* __restrict__ nbri) {
#pragma unroll
    for (int idx = tid; idx < 4096; idx += NTHR) {
        int el = idx >> 5;                 // edge-local 0..127
        int part = idx & 31;               // 0..15 self cols, 16..31 nbr cols
        int edge = tile * 128 + el;
        int node = (part < 16) ? selfi[edge] : nbri[edge];
        int c4 = (part & 15) << 2;
        int col0 = ((part >> 4) << 6) + c4;
        ushort4 sv;
        if (TAB) {
            sv = *(const ushort4*)(fea16 + node * 64 + c4);
        } else {
            float4 fv = *(const float4*)(fea + node * 64 + c4);
            sv.x = f2bf(fv.x); sv.y = f2bf(fv.y); sv.z = f2bf(fv.z); sv.w = f2bf(fv.w);
        }
        *(ushort4*)(Al + el * 136 + col0) = sv;
    }
}

// ---------------- K2: gate logits for ALL 3 heads + segment max ----------------
// 384 threads = 6 waves. Wave w owns head (w>>1), nt-blocks (w&1)*4 .. +3 (64 hidden cols).
// W1 fragments live in registers (tile-invariant); LDS traffic per tile = A only.
template <bool TAB>
__global__ __launch_bounds__(384, 3) void k_gate(
    const float* __restrict__ fea, const u16* __restrict__ fea16,
    const int* __restrict__ selfi, const int* __restrict__ nbri,
    const float* __restrict__ gw1, const float* __restrict__ gb1,
    const float* __restrict__ gw2, const float* __restrict__ gb2,
    float* __restrict__ g_out, u32* __restrict__ gmaxk) {
    __shared__ u16 Al[128 * 136];
    __shared__ float gpart[6][128];
    const int tid = threadIdx.x;
    const int w = tid >> 6, l = tid & 63, q = l >> 4, c = l & 15;
    const int hw = w >> 1;                  // head of this wave
    const int ntb = (w & 1) * 4;            // first nt-block (of 8) within head

    // hoist gate W1 B-fragments: wf[t][kk] covers hidden col (ntb+t)*16+c, k = kk*32+q*8+j
    bf16x8 wf[4][4];
    {
        const float* W = gw1 + hw * 16384;
#pragma unroll
        for (int t = 0; t < 4; ++t)
#pragma unroll
            for (int kk = 0; kk < 4; ++kk)
                wf[t][kk] = load_bfrag<128>(W + (kk * 32 + q * 8) * 128 + (ntb + t) * 16 + c);
    }
    float b1v[4], w2v[4];
#pragma unroll
    for (int t = 0; t < 4; ++t) {
        b1v[t] = gb1[hw * 128 + (ntb + t) * 16 + c];
        w2v[t] = gw2[hw * 128 + (ntb + t) * 16 + c];
    }

    for (int tile = blockIdx.x; tile < NTILES; tile += gridDim.x) {
        stage_A<TAB, 384>(Al, tile, tid, fea, fea16, selfi, nbri);
        __syncthreads();

#pragma unroll
        for (int eb = 0; eb < 8; ++eb) {
            const u16* arow = Al + (eb * 16 + c) * 136 + q * 8;
            bf16x8 a0 = *(const bf16x8*)(arow);
            bf16x8 a1 = *(const bf16x8*)(arow + 32);
            bf16x8 a2 = *(const bf16x8*)(arow + 64);
            bf16x8 a3 = *(const bf16x8*)(arow + 96);
            float gp[4] = {0.f, 0.f, 0.f, 0.f};
#pragma unroll
            for (int t = 0; t < 4; ++t) {
                f32x4 acc = {0.f, 0.f, 0.f, 0.f};
                acc = __builtin_amdgcn_mfma_f32_16x16x32_bf16(a0, wf[t][0], acc, 0, 0, 0);
                acc = __builtin_amdgcn_mfma_f32_16x16x32_bf16(a1, wf[t][1], acc, 0, 0, 0);
                acc = __builtin_amdgcn_mfma_f32_16x16x32_bf16(a2, wf[t][2], acc, 0, 0, 0);
                acc = __builtin_amdgcn_mfma_f32_16x16x32_bf16(a3, wf[t][3], acc, 0, 0, 0);
#pragma unroll
                for (int r = 0; r < 4; ++r)
                    gp[r] += lrelu(acc[r] + b1v[t]) * w2v[t];
            }
            // sum over the 16 c-lanes (lane bits 0..3)
#pragma unroll
            for (int m = 1; m < 16; m <<= 1) {
#pragma unroll
                for (int r = 0; r < 4; ++r) gp[r] += __shfl_xor(gp[r], m, 64);
            }
            if (c == 0) {
#pragma unroll
                for (int r = 0; r < 4; ++r) gpart[w][eb * 16 + q * 4 + r] = gp[r];
            }
        }
        __syncthreads();

        if (tid < 128) {
            int e = tile * 128 + tid;
            int s = selfi[e];
#pragma unroll
            for (int h = 0; h < 3; ++h) {
                float g = gpart[2 * h][tid] + gpart[2 * h + 1][tid] + gb2[h];
                g_out[h * NEDGE + e] = g;
                atomicMax(gmaxk + h * NNODE + s, encf(g));
            }
        }
        __syncthreads();
    }
}

// ---------------- K3: e = w*exp(g-gmax) (in place), denom += e ----------------
__global__ void k_denom(const float* __restrict__ ew,
                        const int* __restrict__ selfi, const int* __restrict__ nbri,
                        float* __restrict__ e_buf, const u32* __restrict__ gmaxk,
                        float* __restrict__ denom) {
    int t = blockIdx.x * 256 + threadIdx.x;   // M/4 threads
    int e0 = t * 4;
    int4 s4 = *(const int4*)(selfi + e0);
    int4 n4 = *(const int4*)(nbri + e0);
    float w0 = ew[n4.x], w1 = ew[n4.y], w2 = ew[n4.z], w3 = ew[n4.w];
#pragma unroll
    for (int h = 0; h < 3; ++h) {
        float4 g4 = *(const float4*)(e_buf + h * NEDGE + e0);
        const u32* gm = gmaxk + h * NNODE;
        float v0 = w0 * __expf(g4.x - decf(gm[s4.x]));
        float v1 = w1 * __expf(g4.y - decf(gm[s4.y]));
        float v2 = w2 * __expf(g4.z - decf(gm[s4.z]));
        float v3 = w3 * __expf(g4.w - decf(gm[s4.w]));
        float4 o = {v0, v1, v2, v3};
        *(float4*)(e_buf + h * NEDGE + e0) = o;
        float* dn = denom + h * NNODE;
        if (s4.x == s4.y) v1 += v0; else atomicAdd(dn + s4.x, v0);
        if (s4.y == s4.z) v2 += v1; else atomicAdd(dn + s4.y, v1);
        if (s4.z == s4.w) v3 += v2; else atomicAdd(dn + s4.z, v2);
        atomicAdd(dn + s4.w, v3);
    }
}

// ---------------- K4: messages + attn scatter (per head; W frags in registers) ----------------
// 512 thr = 8 waves. GEMM1: wave = (egrp1 = w&1 -> ebs egrp1*4..+3) x (hgrp = w>>1 -> nts 2h,2h+1).
// GEMM2: wave = (n2 = w&3) x (eg2 = w>>2 -> ebs eg2*4..+3).
template <bool TAB>
__global__ __launch_bounds__(512, 4) void k_msg(
    const float* __restrict__ fea, const u16* __restrict__ fea16,
    const int* __restrict__ selfi, const int* __restrict__ nbri,
    const float* __restrict__ mw1, const float* __restrict__ mb1,
    const float* __restrict__ mw2, const float* __restrict__ mb2,
    const float* __restrict__ e_buf, const float* __restrict__ denom,
    float* __restrict__ out) {
    __shared__ u16 Al[128 * 136];
    __shared__ u16 Hl[128 * 136];
    __shared__ float attn_l[128];
    __shared__ int self_l[128];
    const int h = blockIdx.y;
    const int tid = threadIdx.x;
    const int w = tid >> 6, l = tid & 63, q = l >> 4, c = l & 15;
    const int hgrp = w >> 1, eg1 = w & 1;
    const int n2 = w & 3, eg2 = w >> 2;

    bf16x8 w1f[2][4];     // [t][kk], hidden col (hgrp*2+t)*16+c
    {
        const float* W1 = mw1 + h * 16384;
#pragma unroll
        for (int t = 0; t < 2; ++t)
#pragma unroll
            for (int kk = 0; kk < 4; ++kk)
                w1f[t][kk] = load_bfrag<128>(W1 + (kk * 32 + q * 8) * 128 + (hgrp * 2 + t) * 16 + c);
    }
    bf16x8 w2f[4];        // [kk], out col n2*16+c
    {
        const float* W2 = mw2 + h * 8192;
#pragma unroll
        for (int kk = 0; kk < 4; ++kk)
            w2f[kk] = load_bfrag<64>(W2 + (kk * 32 + q * 8) * 64 + n2 * 16 + c);
    }
    float b1v[2];
#pragma unroll
    for (int t = 0; t < 2; ++t) b1v[t] = mb1[h * 128 + (hgrp * 2 + t) * 16 + c];
    const float b2v = mb2[h * 64 + n2 * 16 + c];

    for (int tile = blockIdx.x; tile < NTILES; tile += gridDim.x) {
        stage_A<TAB, 512>(Al, tile, tid, fea, fea16, selfi, nbri);
        if (tid < 128) {
            int e = tile * 128 + tid;
            int s = selfi[e];
            self_l[tid] = s;
            attn_l[tid] = e_buf[h * NEDGE + e] / (denom[h * NNODE + s] + 1e-10f) * (1.f / 3.f);
        }
        __syncthreads();

        // ---- GEMM1: A(128x128) x W1 -> H, wave writes its (eb in eg1, nt in hgrp) blocks
#pragma unroll
        for (int ebi = 0; ebi < 4; ++ebi) {
            int eb = eg1 * 4 + ebi;
            const u16* arow = Al + (eb * 16 + c) * 136 + q * 8;
            bf16x8 a0 = *(const bf16x8*)(arow);
            bf16x8 a1 = *(const bf16x8*)(arow + 32);
            bf16x8 a2 = *(const bf16x8*)(arow + 64);
            bf16x8 a3 = *(const bf16x8*)(arow + 96);
#pragma unroll
            for (int t = 0; t < 2; ++t) {
                f32x4 acc = {0.f, 0.f, 0.f, 0.f};
                acc = __builtin_amdgcn_mfma_f32_16x16x32_bf16(a0, w1f[t][0], acc, 0, 0, 0);
                acc = __builtin_amdgcn_mfma_f32_16x16x32_bf16(a1, w1f[t][1], acc, 0, 0, 0);
                acc = __builtin_amdgcn_mfma_f32_16x16x32_bf16(a2, w1f[t][2], acc, 0, 0, 0);
                acc = __builtin_amdgcn_mfma_f32_16x16x32_bf16(a3, w1f[t][3], acc, 0, 0, 0);
                int col = (hgrp * 2 + t) * 16 + c;
                u16* hp = Hl + (eb * 16 + q * 4) * 136 + col;
#pragma unroll
                for (int r = 0; r < 4; ++r)
                    hp[r * 136] = f2bf(lrelu(acc[r] + b1v[t]));
            }
        }
        __syncthreads();

        // ---- GEMM2: H(128x128) x W2 -> m, wave = (n2, eg2); epilogue scatters
#pragma unroll
        for (int ebi = 0; ebi < 4; ++ebi) {
            int eb = eg2 * 4 + ebi;
            const u16* hrow = Hl + (eb * 16 + c) * 136 + q * 8;
            bf16x8 h0 = *(const bf16x8*)(hrow);
            bf16x8 h1 = *(const bf16x8*)(hrow + 32);
            bf16x8 h2 = *(const bf16x8*)(hrow + 64);
            bf16x8 h3 = *(const bf16x8*)(hrow + 96);
            f32x4 m = {0.f, 0.f, 0.f, 0.f};
            m = __builtin_amdgcn_mfma_f32_16x16x32_bf16(h0, w2f[0], m, 0, 0, 0);
            m = __builtin_amdgcn_mfma_f32_16x16x32_bf16(h1, w2f[1], m, 0, 0, 0);
            m = __builtin_amdgcn_mfma_f32_16x16x32_bf16(h2, w2f[2], m, 0, 0, 0);
            m = __builtin_amdgcn_mfma_f32_16x16x32_bf16(h3, w2f[3], m, 0, 0, 0);

            int rb = eb * 16 + q * 4;
            int s0 = self_l[rb], s1 = self_l[rb + 1], s2 = self_l[rb + 2], s3 = self_l[rb + 3];
            float a0 = attn_l[rb], a1 = attn_l[rb + 1], a2v = attn_l[rb + 2], a3 = attn_l[rb + 3];
            int col = n2 * 16 + c;
            float v0 = a0 * (m[0] + b2v);
            float v1 = a1 * (m[1] + b2v);
            float v2 = a2v * (m[2] + b2v);
            float v3 = a3 * (m[3] + b2v);
            if (s0 == s1) v1 += v0; else atomicAdd(out + s0 * 64 + col, v0);
            if (s1 == s2) v2 += v1; else atomicAdd(out + s1 * 64 + col, v1);
            if (s2 == s3) v3 += v2; else atomicAdd(out + s2 * 64 + col, v2);
            atomicAdd(out + s3 * 64 + col, v3);
        }
        __syncthreads();
    }
}

extern "C" void kernel_launch(void* const* d_in, const int* in_sizes, int n_in,
                              void* d_out, int out_size, void* d_ws, size_t ws_size,
                              hipStream_t stream) {
    const float* ew   = (const float*)d_in[0];
    const float* fea  = (const float*)d_in[1];
    const int* selfi  = (const int*)d_in[2];
    const int* nbri   = (const int*)d_in[3];
    const float* gw1  = (const float*)d_in[4];
    const float* gb1  = (const float*)d_in[5];
    const float* gw2  = (const float*)d_in[6];
    const float* gb2  = (const float*)d_in[7];
    const float* mw1  = (const float*)d_in[8];
    const float* mb1  = (const float*)d_in[9];
    const float* mw2  = (const float*)d_in[10];
    const float* mb2  = (const float*)d_in[11];
    float* out = (float*)d_out;
    char* ws = (char*)d_ws;

    float* e_buf = (float*)ws;                 // 3*M f32   (g, then e in place)
    u32* gmaxk   = (u32*)(ws + 12582912);      // 3*N u32
    float* denom = (float*)(ws + 15728640);    // 3*N f32
    u16* fea16   = (u16*)(ws + 18874368);      // N*64 bf16 (optional)
    const bool tab = ws_size >= (size_t)52428800;

    if (tab) {
        k_init<true><<<dim3(16384), dim3(256), 0, stream>>>(fea, out, gmaxk, denom, fea16);
        k_gate<true><<<dim3(512), dim3(384), 0, stream>>>(fea, fea16, selfi, nbri,
                                                          gw1, gb1, gw2, gb2, e_buf, gmaxk);
    } else {
        k_init<false><<<dim3(16384), dim3(256), 0, stream>>>(fea, out, gmaxk, denom, fea16);
        k_gate<false><<<dim3(512), dim3(384), 0, stream>>>(fea, fea16, selfi, nbri,
                                                           gw1, gb1, gw2, gb2, e_buf, gmaxk);
    }
    k_denom<<<dim3(1024), dim3(256), 0, stream>>>(ew, selfi, nbri, e_buf, gmaxk, denom);
    if (tab) {
        k_msg<true><<<dim3(512, 3), dim3(512), 0, stream>>>(fea, fea16, selfi, nbri,
                                                            mw1, mb1, mw2, mb2, e_buf, denom, out);
    } else {
        k_msg<false><<<dim3(512, 3), dim3(512), 0, stream>>>(fea, fea16, selfi, nbri,
                                                             mw1, mb1, mw2, mb2, e_buf, denom, out);
    }
}

// Round 3
// 885.031 us; speedup vs baseline: 1.2585x; 1.0182x over previous
//
#include <hip/hip_runtime.h>

#define NNODE 262144
#define NEDGE 1048576
#define NTILES 8192
#define NEG 0.01f

typedef __bf16 bf16x8 __attribute__((ext_vector_type(8)));
typedef float f32x4 __attribute__((ext_vector_type(4)));
typedef unsigned short u16;
typedef u16 u16x8 __attribute__((ext_vector_type(8)));
typedef unsigned int u32;

__device__ __forceinline__ u16 f2bf(float f) {
    u32 u = __float_as_uint(f);
    u = u + 0x7FFFu + ((u >> 16) & 1u);   // RNE
    return (u16)(u >> 16);
}
// order-preserving float->uint encoding for atomicMax; key 0 == "empty"
__device__ __forceinline__ u32 encf(float f) {
    u32 u = __float_as_uint(f);
    return (u & 0x80000000u) ? ~u : (u | 0x80000000u);
}
__device__ __forceinline__ float decf(u32 k) {
    return (k & 0x80000000u) ? __uint_as_float(k ^ 0x80000000u) : __uint_as_float(~k);
}
__device__ __forceinline__ float lrelu(float x) { return x >= 0.f ? x : NEG * x; }

// load a bf16 MFMA fragment (A- or B-role; both use lane->(row/col=lane&15, k=(lane>>4)*8+j))
// from a global f32 matrix stored [K][Ncols], ld = Ncols. p = W + k0*ld + col.
template <int LD>
__device__ __forceinline__ bf16x8 load_bfrag(const float* __restrict__ p) {
    u16x8 t;
#pragma unroll
    for (int j = 0; j < 8; ++j) t[j] = f2bf(p[j * LD]);
    return __builtin_bit_cast(bf16x8, t);
}

// ---------------- K1: init out / gmax / denom (+ optional bf16 fea table) ----------------
template <bool TAB>
__global__ void k_init(const float* __restrict__ fea, float* __restrict__ out,
                       u32* __restrict__ gmaxk, float* __restrict__ denom,
                       u16* __restrict__ fea16) {
    int i = blockIdx.x * 256 + threadIdx.x;         // exactly N*16 float4 units
    float4 v = ((const float4*)fea)[i];
    ((float4*)out)[i] = v;                          // out starts at elem_in_fea
    if (TAB) {
        ushort4 s;
        s.x = f2bf(v.x); s.y = f2bf(v.y); s.z = f2bf(v.z); s.w = f2bf(v.w);
        ((ushort4*)fea16)[i] = s;
    }
    if (i < 3 * NNODE) { gmaxk[i] = 0u; denom[i] = 0.f; }
}

// ---------------- staging: 128 edges x 128 cols bf16 into LDS (pad 136), b128 writes ----------------
template <bool TAB, int NTHR>
__device__ __forceinline__ void stage_A(u16* Al, int tile, int tid,
                                        const float* __restrict__ fea,
                                        const u16* __restrict__ fea16,
                                        const int* __restrict__ selfi,
                                        const int* __restrict__ nbri) {
    for (int idx = tid; idx < 2048; idx += NTHR) {
        int el = idx >> 4;                 // edge-local 0..127
        int part = idx & 15;               // 0..7 self halves, 8..15 nbr halves
        int edge = tile * 128 + el;
        int node = (part < 8) ? selfi[edge] : nbri[edge];
        int c8 = (part & 7) << 3;          // u16 col within node row
        int col0 = ((part >> 3) << 6) + c8;
        u16x8 sv;
        if (TAB) {
            sv = *(const u16x8*)(fea16 + node * 64 + c8);
        } else {
            float4 f0 = *(const float4*)(fea + node * 64 + c8);
            float4 f1 = *(const float4*)(fea + node * 64 + c8 + 4);
            sv[0] = f2bf(f0.x); sv[1] = f2bf(f0.y); sv[2] = f2bf(f0.z); sv[3] = f2bf(f0.w);
            sv[4] = f2bf(f1.x); sv[5] = f2bf(f1.y); sv[6] = f2bf(f1.z); sv[7] = f2bf(f1.w);
        }
        *(u16x8*)(Al + el * 136 + col0) = sv;
    }
}

// ---------------- K2: gate logits for ALL 3 heads + segment max (unchanged from R2) ----------------
template <bool TAB>
__global__ __launch_bounds__(384, 3) void k_gate(
    const float* __restrict__ fea, const u16* __restrict__ fea16,
    const int* __restrict__ selfi, const int* __restrict__ nbri,
    const float* __restrict__ gw1, const float* __restrict__ gb1,
    const float* __restrict__ gw2, const float* __restrict__ gb2,
    float* __restrict__ g_out, u32* __restrict__ gmaxk) {
    __shared__ u16 Al[128 * 136];
    __shared__ float gpart[6][128];
    const int tid = threadIdx.x;
    const int w = tid >> 6, l = tid & 63, q = l >> 4, c = l & 15;
    const int hw = w >> 1;                  // head of this wave
    const int ntb = (w & 1) * 4;            // first nt-block (of 8) within head

    bf16x8 wf[4][4];
    {
        const float* W = gw1 + hw * 16384;
#pragma unroll
        for (int t = 0; t < 4; ++t)
#pragma unroll
            for (int kk = 0; kk < 4; ++kk)
                wf[t][kk] = load_bfrag<128>(W + (kk * 32 + q * 8) * 128 + (ntb + t) * 16 + c);
    }
    float b1v[4], w2v[4];
#pragma unroll
    for (int t = 0; t < 4; ++t) {
        b1v[t] = gb1[hw * 128 + (ntb + t) * 16 + c];
        w2v[t] = gw2[hw * 128 + (ntb + t) * 16 + c];
    }

    for (int tile = blockIdx.x; tile < NTILES; tile += gridDim.x) {
        stage_A<TAB, 384>(Al, tile, tid, fea, fea16, selfi, nbri);
        __syncthreads();

#pragma unroll
        for (int eb = 0; eb < 8; ++eb) {
            const u16* arow = Al + (eb * 16 + c) * 136 + q * 8;
            bf16x8 a0 = *(const bf16x8*)(arow);
            bf16x8 a1 = *(const bf16x8*)(arow + 32);
            bf16x8 a2 = *(const bf16x8*)(arow + 64);
            bf16x8 a3 = *(const bf16x8*)(arow + 96);
            float gp[4] = {0.f, 0.f, 0.f, 0.f};
#pragma unroll
            for (int t = 0; t < 4; ++t) {
                f32x4 acc = {0.f, 0.f, 0.f, 0.f};
                acc = __builtin_amdgcn_mfma_f32_16x16x32_bf16(a0, wf[t][0], acc, 0, 0, 0);
                acc = __builtin_amdgcn_mfma_f32_16x16x32_bf16(a1, wf[t][1], acc, 0, 0, 0);
                acc = __builtin_amdgcn_mfma_f32_16x16x32_bf16(a2, wf[t][2], acc, 0, 0, 0);
                acc = __builtin_amdgcn_mfma_f32_16x16x32_bf16(a3, wf[t][3], acc, 0, 0, 0);
#pragma unroll
                for (int r = 0; r < 4; ++r)
                    gp[r] += lrelu(acc[r] + b1v[t]) * w2v[t];
            }
#pragma unroll
            for (int m = 1; m < 16; m <<= 1) {
#pragma unroll
                for (int r = 0; r < 4; ++r) gp[r] += __shfl_xor(gp[r], m, 64);
            }
            if (c == 0) {
#pragma unroll
                for (int r = 0; r < 4; ++r) gpart[w][eb * 16 + q * 4 + r] = gp[r];
            }
        }
        __syncthreads();

        if (tid < 128) {
            int e = tile * 128 + tid;
            int s = selfi[e];
#pragma unroll
            for (int h = 0; h < 3; ++h) {
                float g = gpart[2 * h][tid] + gpart[2 * h + 1][tid] + gb2[h];
                g_out[h * NEDGE + e] = g;
                atomicMax(gmaxk + h * NNODE + s, encf(g));
            }
        }
        __syncthreads();
    }
}

// ---------------- K3: e = w*exp(g-gmax) (in place), denom += e ----------------
__global__ void k_denom(const float* __restrict__ ew,
                        const int* __restrict__ selfi, const int* __restrict__ nbri,
                        float* __restrict__ e_buf, const u32* __restrict__ gmaxk,
                        float* __restrict__ denom) {
    int t = blockIdx.x * 256 + threadIdx.x;   // M/4 threads
    int e0 = t * 4;
    int4 s4 = *(const int4*)(selfi + e0);
    int4 n4 = *(const int4*)(nbri + e0);
    float w0 = ew[n4.x], w1 = ew[n4.y], w2 = ew[n4.z], w3 = ew[n4.w];
#pragma unroll
    for (int h = 0; h < 3; ++h) {
        float4 g4 = *(const float4*)(e_buf + h * NEDGE + e0);
        const u32* gm = gmaxk + h * NNODE;
        float v0 = w0 * __expf(g4.x - decf(gm[s4.x]));
        float v1 = w1 * __expf(g4.y - decf(gm[s4.y]));
        float v2 = w2 * __expf(g4.z - decf(gm[s4.z]));
        float v3 = w3 * __expf(g4.w - decf(gm[s4.w]));
        float4 o = {v0, v1, v2, v3};
        *(float4*)(e_buf + h * NEDGE + e0) = o;
        float* dn = denom + h * NNODE;
        if (s4.x == s4.y) v1 += v0; else atomicAdd(dn + s4.x, v0);
        if (s4.y == s4.z) v2 += v1; else atomicAdd(dn + s4.y, v1);
        if (s4.z == s4.w) v3 += v2; else atomicAdd(dn + s4.z, v2);
        atomicAdd(dn + s4.w, v3);
    }
}

// ---------------- K4: messages + attn scatter ----------------
// 512 thr = 8 waves, per head (blockIdx.y).
// GEMM1 (swapped, H^T = W1^T x A^T): wave w owns ebs (w&1)*4..+3, hidden t-pair (w>>1)*2..+1.
//   C layout: col=edge (lane&15), row=hidden q*4+r (consecutive) -> packed ds_write_b64 to H[edge][hid].
// GEMM2 (m = H x W2): wave w owns ebs (w>>1)*2..+1, n2 pair (w&1)*2..+1.
template <bool TAB>
__global__ __launch_bounds__(512, 4) void k_msg(
    const float* __restrict__ fea, const u16* __restrict__ fea16,
    const int* __restrict__ selfi, const int* __restrict__ nbri,
    const float* __restrict__ mw1, const float* __restrict__ mb1,
    const float* __restrict__ mw2, const float* __restrict__ mb2,
    const float* __restrict__ e_buf, const float* __restrict__ denom,
    float* __restrict__ out) {
    __shared__ u16 Al[128 * 136];
    __shared__ u16 Hl[128 * 136];
    __shared__ float attn_l[2][128];
    __shared__ int self_l[2][128];
    const int h = blockIdx.y;
    const int tid = threadIdx.x;
    const int w = tid >> 6, l = tid & 63, q = l >> 4, c = l & 15;
    const int eg1 = w & 1, tg = w >> 1;        // GEMM1: 4 ebs, 2 hidden blocks
    const int eg2 = w >> 1, ng = w & 1;        // GEMM2: 2 ebs, 2 n2 blocks

    bf16x8 w1f[2][4];     // [t'][kk], A-role frag of W1^T: row = hid (tg*2+t')*16+c, k = kk*32+q*8+j
    {
        const float* W1 = mw1 + h * 16384;
#pragma unroll
        for (int t = 0; t < 2; ++t)
#pragma unroll
            for (int kk = 0; kk < 4; ++kk)
                w1f[t][kk] = load_bfrag<128>(W1 + (kk * 32 + q * 8) * 128 + (tg * 2 + t) * 16 + c);
    }
    bf16x8 w2f[2][4];     // [n2'][kk], B-role frag: col = (ng*2+n2')*16+c
    {
        const float* W2 = mw2 + h * 8192;
#pragma unroll
        for (int n2 = 0; n2 < 2; ++n2)
#pragma unroll
            for (int kk = 0; kk < 4; ++kk)
                w2f[n2][kk] = load_bfrag<64>(W2 + (kk * 32 + q * 8) * 64 + (ng * 2 + n2) * 16 + c);
    }
    float4 b1q[2];        // bias for hidden rows (tg*2+t')*16 + q*4 .. +3
#pragma unroll
    for (int t = 0; t < 2; ++t)
        b1q[t] = *(const float4*)(mb1 + h * 128 + (tg * 2 + t) * 16 + q * 4);
    float b2v[2];
#pragma unroll
    for (int n2 = 0; n2 < 2; ++n2) b2v[n2] = mb2[h * 64 + (ng * 2 + n2) * 16 + c];

    int pb = 0;
    for (int tile = blockIdx.x; tile < NTILES; tile += gridDim.x, pb ^= 1) {
        stage_A<TAB, 512>(Al, tile, tid, fea, fea16, selfi, nbri);
        if (tid < 128) {
            int e = tile * 128 + tid;
            int s = selfi[e];
            self_l[pb][tid] = s;
            attn_l[pb][tid] = e_buf[h * NEDGE + e] / (denom[h * NNODE + s] + 1e-10f) * (1.f / 3.f);
        }
        __syncthreads();   // A + attn ready; Hl free (all waves past GEMM2 of prev tile)

        // ---- GEMM1 swapped: per (eb, t'): C[row=hid, col=edge]; packed b64 H-write
#pragma unroll
        for (int ebi = 0; ebi < 4; ++ebi) {
            int eb = eg1 * 4 + ebi;
            const u16* arow = Al + (eb * 16 + c) * 136 + q * 8;
            bf16x8 a0 = *(const bf16x8*)(arow);
            bf16x8 a1 = *(const bf16x8*)(arow + 32);
            bf16x8 a2 = *(const bf16x8*)(arow + 64);
            bf16x8 a3 = *(const bf16x8*)(arow + 96);
#pragma unroll
            for (int t = 0; t < 2; ++t) {
                f32x4 acc = {0.f, 0.f, 0.f, 0.f};
                acc = __builtin_amdgcn_mfma_f32_16x16x32_bf16(w1f[t][0], a0, acc, 0, 0, 0);
                acc = __builtin_amdgcn_mfma_f32_16x16x32_bf16(w1f[t][1], a1, acc, 0, 0, 0);
                acc = __builtin_amdgcn_mfma_f32_16x16x32_bf16(w1f[t][2], a2, acc, 0, 0, 0);
                acc = __builtin_amdgcn_mfma_f32_16x16x32_bf16(w1f[t][3], a3, acc, 0, 0, 0);
                ushort4 hv;
                hv.x = f2bf(lrelu(acc[0] + b1q[t].x));
                hv.y = f2bf(lrelu(acc[1] + b1q[t].y));
                hv.z = f2bf(lrelu(acc[2] + b1q[t].z));
                hv.w = f2bf(lrelu(acc[3] + b1q[t].w));
                *(ushort4*)(Hl + (eb * 16 + c) * 136 + (tg * 2 + t) * 16 + q * 4) = hv;
            }
        }
        __syncthreads();   // H ready; Al free for next stage

        // ---- GEMM2: per (eb, n2'): m = H x W2; epilogue scatters with sorted-run dedup
#pragma unroll
        for (int ebi = 0; ebi < 2; ++ebi) {
            int eb = eg2 * 2 + ebi;
            const u16* hrow = Hl + (eb * 16 + c) * 136 + q * 8;
            bf16x8 h0 = *(const bf16x8*)(hrow);
            bf16x8 h1 = *(const bf16x8*)(hrow + 32);
            bf16x8 h2 = *(const bf16x8*)(hrow + 64);
            bf16x8 h3 = *(const bf16x8*)(hrow + 96);
            int rb = eb * 16 + q * 4;
            int s0 = self_l[pb][rb], s1 = self_l[pb][rb + 1];
            int s2 = self_l[pb][rb + 2], s3 = self_l[pb][rb + 3];
            float a0 = attn_l[pb][rb], a1 = attn_l[pb][rb + 1];
            float a2v = attn_l[pb][rb + 2], a3 = attn_l[pb][rb + 3];
#pragma unroll
            for (int n2 = 0; n2 < 2; ++n2) {
                f32x4 m = {0.f, 0.f, 0.f, 0.f};
                m = __builtin_amdgcn_mfma_f32_16x16x32_bf16(h0, w2f[n2][0], m, 0, 0, 0);
                m = __builtin_amdgcn_mfma_f32_16x16x32_bf16(h1, w2f[n2][1], m, 0, 0, 0);
                m = __builtin_amdgcn_mfma_f32_16x16x32_bf16(h2, w2f[n2][2], m, 0, 0, 0);
                m = __builtin_amdgcn_mfma_f32_16x16x32_bf16(h3, w2f[n2][3], m, 0, 0, 0);
                int col = (ng * 2 + n2) * 16 + c;
                float v0 = a0 * (m[0] + b2v[n2]);
                float v1 = a1 * (m[1] + b2v[n2]);
                float v2 = a2v * (m[2] + b2v[n2]);
                float v3 = a3 * (m[3] + b2v[n2]);
                if (s0 == s1) v1 += v0; else atomicAdd(out + s0 * 64 + col, v0);
                if (s1 == s2) v2 += v1; else atomicAdd(out + s1 * 64 + col, v1);
                if (s2 == s3) v3 += v2; else atomicAdd(out + s2 * 64 + col, v2);
                atomicAdd(out + s3 * 64 + col, v3);
            }
        }
        // no third barrier: next stage writes Al (free) and attn[pb^1]; Hl writes of next
        // GEMM1 are fenced by the next __syncthreads after staging.
    }
}

extern "C" void kernel_launch(void* const* d_in, const int* in_sizes, int n_in,
                              void* d_out, int out_size, void* d_ws, size_t ws_size,
                              hipStream_t stream) {
    const float* ew   = (const float*)d_in[0];
    const float* fea  = (const float*)d_in[1];
    const int* selfi  = (const int*)d_in[2];
    const int* nbri   = (const int*)d_in[3];
    const float* gw1  = (const float*)d_in[4];
    const float* gb1  = (const float*)d_in[5];
    const float* gw2  = (const float*)d_in[6];
    const float* gb2  = (const float*)d_in[7];
    const float* mw1  = (const float*)d_in[8];
    const float* mb1  = (const float*)d_in[9];
    const float* mw2  = (const float*)d_in[10];
    const float* mb2  = (const float*)d_in[11];
    float* out = (float*)d_out;
    char* ws = (char*)d_ws;

    float* e_buf = (float*)ws;                 // 3*M f32   (g, then e in place)
    u32* gmaxk   = (u32*)(ws + 12582912);      // 3*N u32
    float* denom = (float*)(ws + 15728640);    // 3*N f32
    u16* fea16   = (u16*)(ws + 18874368);      // N*64 bf16 (optional)
    const bool tab = ws_size >= (size_t)52428800;

    if (tab) {
        k_init<true><<<dim3(16384), dim3(256), 0, stream>>>(fea, out, gmaxk, denom, fea16);
        k_gate<true><<<dim3(512), dim3(384), 0, stream>>>(fea, fea16, selfi, nbri,
                                                          gw1, gb1, gw2, gb2, e_buf, gmaxk);
    } else {
        k_init<false><<<dim3(16384), dim3(256), 0, stream>>>(fea, out, gmaxk, denom, fea16);
        k_gate<false><<<dim3(512), dim3(384), 0, stream>>>(fea, fea16, selfi, nbri,
                                                           gw1, gb1, gw2, gb2, e_buf, gmaxk);
    }
    k_denom<<<dim3(1024), dim3(256), 0, stream>>>(ew, selfi, nbri, e_buf, gmaxk, denom);
    if (tab) {
        k_msg<true><<<dim3(512, 3), dim3(512), 0, stream>>>(fea, fea16, selfi, nbri,
                                                            mw1, mb1, mw2, mb2, e_buf, denom, out);
    } else {
        k_msg<false><<<dim3(512, 3), dim3(512), 0, stream>>>(fea, fea16, selfi, nbri,
                                                             mw1, mb1, mw2, mb2, e_buf, denom, out);
    }
}